// Round 7
// baseline (257.741 us; speedup 1.0000x reference)
//
#include <hip/hip_runtime.h>
#include <hip/hip_cooperative_groups.h>

namespace cg = cooperative_groups;

#define B_N 8192
#define K_CL 64
#define CAP 256
#define NPAIR 2016
#define NBLK 1024
#define INF_F 3.0e38f

// Single cooperative kernel:
//  phase 1: blocks 0..63 ballot-compact cluster c's points into lists[c]
//  phase 2: 1024 blocks x 2 pairs: brute-force min dist, hinge -> hinges[p]
//  phase 3: block 0 reduces 2016 hinges -> out
// ws layout: [0, 64*256 float2) lists | then int cnts[64] | then hinges[2016]

__global__ __launch_bounds__(256) void fused_loss_kernel(
    const int* __restrict__ labels, const float2* __restrict__ coords,
    float2* __restrict__ lists, int* __restrict__ cnts,
    float* __restrict__ hinges, float* __restrict__ out) {
    cg::grid_group grid = cg::this_grid();
    int tid = threadIdx.x;
    int bid = blockIdx.x;
    int lane = tid & 63;
    int wave = tid >> 6;

    __shared__ float2 jpt[CAP];
    __shared__ float wred[4];
    __shared__ int cntS;

    // ---- phase 1: gather (blocks 0..63) ----
    if (bid < K_CL) {
        int c = bid;
        if (tid == 0) cntS = 0;
        __syncthreads();
#pragma unroll
        for (int k = 0; k < 8; ++k) {
            int v4 = tid + k * 256;                       // int4 index
            int4 lb = reinterpret_cast<const int4*>(labels)[v4];
            int lab[4] = {lb.x, lb.y, lb.z, lb.w};
#pragma unroll
            for (int cc = 0; cc < 4; ++cc) {
                bool m = (lab[cc] == c);
                unsigned long long mask = __ballot(m);
                if (mask) {                               // wave-uniform
                    int wb = 0;
                    if (lane == 0) wb = atomicAdd(&cntS, __popcll(mask));
                    wb = __shfl(wb, 0, 64);
                    if (m) {
                        int pos = wb + __popcll(mask & ((1ull << lane) - 1));
                        if (pos < CAP) lists[c * CAP + pos] = coords[v4 * 4 + cc];
                    }
                }
            }
        }
        __syncthreads();
        if (tid == 0) cnts[c] = min(cntS, CAP);
        __threadfence();
    }
    grid.sync();

    // ---- phase 2: pairs (2 per block) ----
    for (int p = bid; p < NPAIR; p += NBLK) {
        // decode p -> (ci, cj), wave-uniform scalar loop
        int ci = 0, rem = p;
        while (rem >= K_CL - 1 - ci) { rem -= K_CL - 1 - ci; ci++; }
        int cj = ci + 1 + rem;
        int nI = cnts[ci], nJ = cnts[cj];
        __syncthreads();                   // jpt/wred safe to overwrite
        if (tid < nJ) jpt[tid] = lists[cj * CAP + tid];
        bool valid = tid < nI;
        float2 pi = make_float2(0.0f, 0.0f);
        if (valid) pi = lists[ci * CAP + tid];
        __syncthreads();

        float m0 = INF_F, m1 = INF_F, m2 = INF_F, m3 = INF_F;
        if (valid) {
            int j = 0;
            for (; j + 3 < nJ; j += 4) {
                float2 a = jpt[j], b = jpt[j + 1], c = jpt[j + 2], d = jpt[j + 3];
                float dx0 = pi.x - a.x, dy0 = pi.y - a.y;
                float dx1 = pi.x - b.x, dy1 = pi.y - b.y;
                float dx2 = pi.x - c.x, dy2 = pi.y - c.y;
                float dx3 = pi.x - d.x, dy3 = pi.y - d.y;
                m0 = fminf(m0, dx0 * dx0 + dy0 * dy0);
                m1 = fminf(m1, dx1 * dx1 + dy1 * dy1);
                m2 = fminf(m2, dx2 * dx2 + dy2 * dy2);
                m3 = fminf(m3, dx3 * dx3 + dy3 * dy3);
            }
            for (; j < nJ; ++j) {
                float dx = pi.x - jpt[j].x, dy = pi.y - jpt[j].y;
                m0 = fminf(m0, dx * dx + dy * dy);
            }
        }
        float myMin = fminf(fminf(m0, m1), fminf(m2, m3));
        for (int off = 32; off > 0; off >>= 1)
            myMin = fminf(myMin, __shfl_down(myMin, off, 64));
        if (lane == 0) wred[wave] = myMin;
        __syncthreads();
        if (tid == 0) {
            float m = fminf(fminf(wred[0], wred[1]), fminf(wred[2], wred[3]));
            float h = 1.0f - sqrtf(m);
            hinges[p] = h > 0.0f ? h : 0.0f;
        }
    }
    __threadfence();
    grid.sync();

    // ---- phase 3: block 0 reduces ----
    if (bid == 0) {
        float s = 0.0f;
        for (int p = tid; p < NPAIR; p += 256) s += hinges[p];
        for (int off = 32; off > 0; off >>= 1)
            s += __shfl_down(s, off, 64);
        if (lane == 0) wred[wave] = s;
        __syncthreads();
        if (tid == 0)
            out[0] = (wred[0] + wred[1] + wred[2] + wred[3]) / (float)NPAIR;
    }
}

extern "C" void kernel_launch(void* const* d_in, const int* in_sizes, int n_in,
                              void* d_out, int out_size, void* d_ws, size_t ws_size,
                              hipStream_t stream) {
    const int*    labels = (const int*)d_in[1];     // cluster_labels (int32)
    const float2* coords = (const float2*)d_in[2];  // manifold_coords [8192,2] f32
    float* out = (float*)d_out;

    float2* lists  = (float2*)d_ws;
    int*    cnts   = (int*)((char*)d_ws + (size_t)2 * K_CL * CAP * sizeof(float));
    float*  hinges = (float*)((char*)cnts + 256);

    void* args[] = {(void*)&labels, (void*)&coords, (void*)&lists,
                    (void*)&cnts, (void*)&hinges, (void*)&out};
    hipLaunchCooperativeKernel((const void*)fused_loss_kernel,
                               dim3(NBLK), dim3(256), args, 0, stream);
}

// Round 8
// 116.660 us; speedup vs baseline: 2.2093x; 2.2093x over previous
//
#include <hip/hip_runtime.h>

#define B_N 8192
#define K_CL 64
#define CAP 256
#define NPAIR 2016
#define NBLK 256
#define INF_F 3.0e38f

// Single regular kernel, producer-consumer via device-scope flags.
//  blocks 0..63: ballot-compact cluster c -> lists[c]; release flags[c]=cnt+1
//  all blocks:   ~8 pairs each (balanced), spin-acquire the two flags,
//                brute-force min dist, hinge -> hinges[p]
//  last block (done counter): reduce 2016 hinges -> out
// ws: lists float2[64*256] | hinges float[2016] | flags int[64] | done int

__global__ __launch_bounds__(256, 1) void fused_kernel(
    const int* __restrict__ labels, const float2* __restrict__ coords,
    float2* __restrict__ lists, float* __restrict__ hinges,
    int* __restrict__ flags, int* __restrict__ done,
    float* __restrict__ out) {
    int tid = threadIdx.x, bid = blockIdx.x;
    int lane = tid & 63, wave = tid >> 6;
    __shared__ float2 jpt[CAP];
    __shared__ float wred[4];
    __shared__ int shA, shB;

    // ---- phase 1: gather (blocks 0..63) ----
    if (bid < K_CL) {
        int c = bid;
        if (tid == 0) shA = 0;
        __syncthreads();
#pragma unroll
        for (int k = 0; k < 8; ++k) {
            int v4 = tid + k * 256;                     // int4 index
            int4 lb = reinterpret_cast<const int4*>(labels)[v4];
            int lab[4] = {lb.x, lb.y, lb.z, lb.w};
#pragma unroll
            for (int cc = 0; cc < 4; ++cc) {
                bool m = (lab[cc] == c);
                unsigned long long mask = __ballot(m);
                if (mask) {                             // wave-uniform
                    int wb = 0;
                    if (lane == 0) wb = atomicAdd(&shA, __popcll(mask));
                    wb = __shfl(wb, 0, 64);
                    if (m) {
                        int pos = wb + __popcll(mask & ((1ull << lane) - 1));
                        if (pos < CAP) lists[c * CAP + pos] = coords[v4 * 4 + cc];
                    }
                }
            }
        }
        __syncthreads();
        if (tid == 0) {
            int n = min(shA, CAP);
            __threadfence();
            __hip_atomic_store(&flags[c], n + 1, __ATOMIC_RELEASE,
                               __HIP_MEMORY_SCOPE_AGENT);
        }
    }

    // ---- phase 2: pairs (statically balanced) ----
    int pbeg  = (bid >= K_CL) ? (bid - K_CL) : (1728 + bid);
    int pstep = (bid >= K_CL) ? 192 : 64;
    int pend  = (bid >= K_CL) ? 1728 : NPAIR;
    for (int p = pbeg; p < pend; p += pstep) {
        int ci = 0, rem = p;                            // decode p -> (ci,cj)
        while (rem >= K_CL - 1 - ci) { rem -= K_CL - 1 - ci; ci++; }
        int cj = ci + 1 + rem;
        if (tid == 0) {
            int fI, fJ;
            while ((fI = __hip_atomic_load(&flags[ci], __ATOMIC_ACQUIRE,
                                           __HIP_MEMORY_SCOPE_AGENT)) == 0)
                __builtin_amdgcn_s_sleep(1);
            while ((fJ = __hip_atomic_load(&flags[cj], __ATOMIC_ACQUIRE,
                                           __HIP_MEMORY_SCOPE_AGENT)) == 0)
                __builtin_amdgcn_s_sleep(1);
            shA = fI - 1; shB = fJ - 1;
        }
        __syncthreads();
        int nI = shA, nJ = shB;
        if (tid < nJ) jpt[tid] = lists[cj * CAP + tid];
        bool valid = tid < nI;
        float2 pi = make_float2(0.0f, 0.0f);
        if (valid) pi = lists[ci * CAP + tid];
        __syncthreads();

        float m0 = INF_F, m1 = INF_F, m2 = INF_F, m3 = INF_F;
        if (valid) {
            int j = 0;
            for (; j + 3 < nJ; j += 4) {
                float2 a = jpt[j], b = jpt[j + 1], c = jpt[j + 2], d = jpt[j + 3];
                float dx0 = pi.x - a.x, dy0 = pi.y - a.y;
                float dx1 = pi.x - b.x, dy1 = pi.y - b.y;
                float dx2 = pi.x - c.x, dy2 = pi.y - c.y;
                float dx3 = pi.x - d.x, dy3 = pi.y - d.y;
                m0 = fminf(m0, dx0 * dx0 + dy0 * dy0);
                m1 = fminf(m1, dx1 * dx1 + dy1 * dy1);
                m2 = fminf(m2, dx2 * dx2 + dy2 * dy2);
                m3 = fminf(m3, dx3 * dx3 + dy3 * dy3);
            }
            for (; j < nJ; ++j) {
                float dx = pi.x - jpt[j].x, dy = pi.y - jpt[j].y;
                m0 = fminf(m0, dx * dx + dy * dy);
            }
        }
        float myMin = fminf(fminf(m0, m1), fminf(m2, m3));
        for (int off = 32; off > 0; off >>= 1)
            myMin = fminf(myMin, __shfl_down(myMin, off, 64));
        if (lane == 0) wred[wave] = myMin;
        __syncthreads();
        if (tid == 0) {
            float m = fminf(fminf(wred[0], wred[1]), fminf(wred[2], wred[3]));
            float h = 1.0f - sqrtf(m);
            hinges[p] = h > 0.0f ? h : 0.0f;
        }
        __syncthreads();                 // jpt/wred safe for next iteration
    }

    // ---- phase 3: last block reduces ----
    __threadfence();
    __syncthreads();
    if (tid == 0) {
        int old = __hip_atomic_fetch_add(done, 1, __ATOMIC_ACQ_REL,
                                         __HIP_MEMORY_SCOPE_AGENT);
        shA = (old == NBLK - 1) ? 1 : 0;
    }
    __syncthreads();
    if (shA) {
        float s = 0.0f;
        for (int p = tid; p < NPAIR; p += 256)
            s += __hip_atomic_load(&hinges[p], __ATOMIC_RELAXED,
                                   __HIP_MEMORY_SCOPE_AGENT);
        for (int off = 32; off > 0; off >>= 1)
            s += __shfl_down(s, off, 64);
        if (lane == 0) wred[wave] = s;
        __syncthreads();
        if (tid == 0)
            out[0] = (wred[0] + wred[1] + wred[2] + wred[3]) / (float)NPAIR;
    }
}

extern "C" void kernel_launch(void* const* d_in, const int* in_sizes, int n_in,
                              void* d_out, int out_size, void* d_ws, size_t ws_size,
                              hipStream_t stream) {
    const int*    labels = (const int*)d_in[1];     // cluster_labels (int32)
    const float2* coords = (const float2*)d_in[2];  // manifold_coords [8192,2] f32
    float* out = (float*)d_out;

    float2* lists  = (float2*)d_ws;                               // 128 KB
    float*  hinges = (float*)((char*)d_ws + 2 * K_CL * CAP * sizeof(float));
    int*    flags  = (int*)((char*)hinges + NPAIR * sizeof(float) + 64);
    int*    done   = flags + K_CL;

    hipMemsetAsync(flags, 0, (K_CL + 1) * sizeof(int), stream);
    fused_kernel<<<NBLK, 256, 0, stream>>>(labels, coords, lists, hinges,
                                           flags, done, out);
}

// Round 9
// 83.991 us; speedup vs baseline: 3.0687x; 1.3890x over previous
//
#include <hip/hip_runtime.h>

#define B_N 8192
#define K_CL 64
#define CAP 256
#define NPAIR 2016
#define INF_F 3.0e38f

// Pipeline (no cross-block waiting; proven-fast components only):
//  1) gather_kernel (64 blocks): ballot-compact cluster c -> lists[c], cnts[c]
//  2) pair_reduce_kernel (2016 blocks, 1-D): min-dist + hinge -> hinges[p];
//     int done-counter; last block sums hinges -> out  (native int RMW,
//     NOT fp32 atomicAdd which CAS-livelocks at this contention - R2 lesson)
// ws: lists float2[64*256] | cnts int[64] | hinges float[2016] | done int

__global__ __launch_bounds__(256) void gather_kernel(
    const int* __restrict__ labels, const float2* __restrict__ coords,
    float2* __restrict__ lists, int* __restrict__ cnts) {
    int c = blockIdx.x;
    __shared__ int cnt;
    int tid = threadIdx.x;
    int lane = tid & 63;
    if (tid == 0) cnt = 0;
    __syncthreads();
#pragma unroll
    for (int k = 0; k < 8; ++k) {
        int v4 = tid + k * 256;                        // int4 index
        int4 lb = reinterpret_cast<const int4*>(labels)[v4];
        int lab[4] = {lb.x, lb.y, lb.z, lb.w};
#pragma unroll
        for (int cc = 0; cc < 4; ++cc) {
            bool m = (lab[cc] == c);
            unsigned long long mask = __ballot(m);
            if (mask) {                                 // wave-uniform
                int wb = 0;
                if (lane == 0) wb = atomicAdd(&cnt, __popcll(mask));
                wb = __shfl(wb, 0, 64);
                if (m) {
                    int pos = wb + __popcll(mask & ((1ull << lane) - 1));
                    if (pos < CAP) lists[c * CAP + pos] = coords[v4 * 4 + cc];
                }
            }
        }
    }
    __syncthreads();
    if (tid == 0) cnts[c] = min(cnt, CAP);
}

__global__ __launch_bounds__(256) void pair_reduce_kernel(
    const float2* __restrict__ lists, const int* __restrict__ cnts,
    float* __restrict__ hinges, int* __restrict__ done,
    float* __restrict__ out) {
    int p = blockIdx.x;                   // 0..2015
    int tid = threadIdx.x;
    int lane = tid & 63, wave = tid >> 6;
    // decode p -> (ci,cj): wave-uniform scalar loop (<=63 iters)
    int ci = 0, rem = p;
    while (rem >= K_CL - 1 - ci) { rem -= K_CL - 1 - ci; ci++; }
    int cj = ci + 1 + rem;
    int nI = cnts[ci], nJ = cnts[cj];

    __shared__ float2 jpt[CAP];
    __shared__ float wred[4];
    __shared__ int lastFlag;
    if (tid < nJ) jpt[tid] = lists[cj * CAP + tid];
    bool valid = tid < nI;
    float2 pi = make_float2(0.0f, 0.0f);
    if (valid) pi = lists[ci * CAP + tid];
    __syncthreads();

    // 4 accumulators to break the fminf dependency chain
    float m0 = INF_F, m1 = INF_F, m2 = INF_F, m3 = INF_F;
    if (valid) {
        int j = 0;
        for (; j + 3 < nJ; j += 4) {
            float2 a = jpt[j], b = jpt[j + 1], c = jpt[j + 2], d = jpt[j + 3];
            float dx0 = pi.x - a.x, dy0 = pi.y - a.y;
            float dx1 = pi.x - b.x, dy1 = pi.y - b.y;
            float dx2 = pi.x - c.x, dy2 = pi.y - c.y;
            float dx3 = pi.x - d.x, dy3 = pi.y - d.y;
            m0 = fminf(m0, dx0 * dx0 + dy0 * dy0);
            m1 = fminf(m1, dx1 * dx1 + dy1 * dy1);
            m2 = fminf(m2, dx2 * dx2 + dy2 * dy2);
            m3 = fminf(m3, dx3 * dx3 + dy3 * dy3);
        }
        for (; j < nJ; ++j) {
            float dx = pi.x - jpt[j].x, dy = pi.y - jpt[j].y;
            m0 = fminf(m0, dx * dx + dy * dy);
        }
    }
    float myMin = fminf(fminf(m0, m1), fminf(m2, m3));
    for (int off = 32; off > 0; off >>= 1)
        myMin = fminf(myMin, __shfl_down(myMin, off, 64));
    if (lane == 0) wred[wave] = myMin;
    __syncthreads();
    if (tid == 0) {
        float m = fminf(fminf(wred[0], wred[1]), fminf(wred[2], wred[3]));
        float h = 1.0f - sqrtf(m);
        hinges[p] = h > 0.0f ? h : 0.0f;
        __threadfence();                  // order hinge store before counter
        int old = __hip_atomic_fetch_add(done, 1, __ATOMIC_ACQ_REL,
                                         __HIP_MEMORY_SCOPE_AGENT);
        lastFlag = (old == NPAIR - 1) ? 1 : 0;
    }
    __syncthreads();

    // last block: reduce all hinges -> out
    if (lastFlag) {
        float s = 0.0f;
        for (int q = tid; q < NPAIR; q += 256)
            s += __hip_atomic_load(&hinges[q], __ATOMIC_RELAXED,
                                   __HIP_MEMORY_SCOPE_AGENT);
        for (int off = 32; off > 0; off >>= 1)
            s += __shfl_down(s, off, 64);
        if (lane == 0) wred[wave] = s;
        __syncthreads();
        if (tid == 0)
            out[0] = (wred[0] + wred[1] + wred[2] + wred[3]) / (float)NPAIR;
    }
}

extern "C" void kernel_launch(void* const* d_in, const int* in_sizes, int n_in,
                              void* d_out, int out_size, void* d_ws, size_t ws_size,
                              hipStream_t stream) {
    const int*    labels = (const int*)d_in[1];     // cluster_labels (int32)
    const float2* coords = (const float2*)d_in[2];  // manifold_coords [8192,2] f32
    float* out = (float*)d_out;

    float2* lists  = (float2*)d_ws;                               // 128 KB
    int*    cnts   = (int*)((char*)d_ws + 2 * K_CL * CAP * sizeof(float));
    float*  hinges = (float*)((char*)cnts + K_CL * sizeof(int) + 64);
    int*    done   = (int*)((char*)hinges + NPAIR * sizeof(float));

    hipMemsetAsync(done, 0, sizeof(int), stream);
    gather_kernel<<<K_CL, 256, 0, stream>>>(labels, coords, lists, cnts);
    pair_reduce_kernel<<<NPAIR, 256, 0, stream>>>(lists, cnts, hinges, done, out);
}

// Round 10
// 47.813 us; speedup vs baseline: 5.3906x; 1.7566x over previous
//
#include <hip/hip_runtime.h>

#define B_N 8192
#define K_CL 64
#define CAP 256
#define NPAIR 2016
#define INF_F 3.0e38f

// 2 launches, no cross-block sync primitives (R7/R8/R9 all proved those
// cost 60-220us on this chip; a kernel boundary costs ~7us):
//  1) pair_kernel (64x64 grid, ci<cj active): each block ballot-compacts
//     BOTH clusters' points from the L2-resident labels/coords into LDS
//     (wave-uniform: 2 lane-0 LDS atomics per 64-point chunk, no per-lane
//     atomic storm - R5 lesson), then brute-forces min dist -> hinges.
//  2) reduce_hinge_kernel (1 block): mean -> out.
// ws layout (floats): [0,4096) hinges[64*64]

__global__ __launch_bounds__(256) void pair_kernel(
    const int* __restrict__ labels, const float2* __restrict__ coords,
    float* __restrict__ hinges) {
    int ci = blockIdx.x, cj = blockIdx.y;
    if (ci >= cj) return;                 // uniform per block
    int tid = threadIdx.x, lane = tid & 63, wave = tid >> 6;
    __shared__ float2 ipts[CAP], jpts[CAP];
    __shared__ float wred[4];
    __shared__ int cntI, cntJ;
    if (tid == 0) { cntI = 0; cntJ = 0; }
    __syncthreads();

    // scan all labels: 8 x int4 per thread (coalesced, L2-hot).
    // Per wave-chunk: ballot both clusters, lane0 reserves LDS slots.
#pragma unroll
    for (int k = 0; k < 8; ++k) {
        int v4 = tid + k * 256;                        // int4 index
        int4 lb = reinterpret_cast<const int4*>(labels)[v4];
        int lab[4] = {lb.x, lb.y, lb.z, lb.w};
#pragma unroll
        for (int cc = 0; cc < 4; ++cc) {
            bool mi = (lab[cc] == ci);
            bool mj = (lab[cc] == cj);
            unsigned long long bi = __ballot(mi);
            unsigned long long bj = __ballot(mj);
            if (bi) {                                   // wave-uniform
                int wb = 0;
                if (lane == 0) wb = atomicAdd(&cntI, __popcll(bi));
                wb = __shfl(wb, 0, 64);
                if (mi) {
                    int pos = wb + __popcll(bi & ((1ull << lane) - 1));
                    if (pos < CAP) ipts[pos] = coords[v4 * 4 + cc];
                }
            }
            if (bj) {                                   // wave-uniform
                int wb = 0;
                if (lane == 0) wb = atomicAdd(&cntJ, __popcll(bj));
                wb = __shfl(wb, 0, 64);
                if (mj) {
                    int pos = wb + __popcll(bj & ((1ull << lane) - 1));
                    if (pos < CAP) jpts[pos] = coords[v4 * 4 + cc];
                }
            }
        }
    }
    __syncthreads();
    int nI = min(cntI, CAP), nJ = min(cntJ, CAP);

    bool valid = tid < nI;
    float2 pi = make_float2(0.0f, 0.0f);
    if (valid) pi = ipts[tid];

    // 4 accumulators to break the fminf dependency chain
    float m0 = INF_F, m1 = INF_F, m2 = INF_F, m3 = INF_F;
    if (valid) {
        int j = 0;
        for (; j + 3 < nJ; j += 4) {
            float2 a = jpts[j], b = jpts[j + 1], c = jpts[j + 2], d = jpts[j + 3];
            float dx0 = pi.x - a.x, dy0 = pi.y - a.y;
            float dx1 = pi.x - b.x, dy1 = pi.y - b.y;
            float dx2 = pi.x - c.x, dy2 = pi.y - c.y;
            float dx3 = pi.x - d.x, dy3 = pi.y - d.y;
            m0 = fminf(m0, dx0 * dx0 + dy0 * dy0);
            m1 = fminf(m1, dx1 * dx1 + dy1 * dy1);
            m2 = fminf(m2, dx2 * dx2 + dy2 * dy2);
            m3 = fminf(m3, dx3 * dx3 + dy3 * dy3);
        }
        for (; j < nJ; ++j) {
            float dx = pi.x - jpts[j].x, dy = pi.y - jpts[j].y;
            m0 = fminf(m0, dx * dx + dy * dy);
        }
    }
    float myMin = fminf(fminf(m0, m1), fminf(m2, m3));
    for (int off = 32; off > 0; off >>= 1)
        myMin = fminf(myMin, __shfl_down(myMin, off, 64));
    if (lane == 0) wred[wave] = myMin;
    __syncthreads();
    if (tid == 0) {
        float m = fminf(fminf(wred[0], wred[1]), fminf(wred[2], wred[3]));
        float h = 1.0f - sqrtf(m);
        hinges[ci * K_CL + cj] = h > 0.0f ? h : 0.0f;
    }
}

__global__ void reduce_hinge_kernel(const float* __restrict__ hinges,
                                    float* __restrict__ out) {
    int tid = threadIdx.x;
    float s = 0.0f;
    for (int p = tid; p < K_CL * K_CL; p += 256) {
        int ci = p >> 6, cj = p & 63;
        if (ci < cj) s += hinges[p];
    }
    for (int off = 32; off > 0; off >>= 1)
        s += __shfl_down(s, off, 64);
    __shared__ float wsum[4];
    int wave = tid >> 6, lane = tid & 63;
    if (lane == 0) wsum[wave] = s;
    __syncthreads();
    if (tid == 0)
        out[0] = (wsum[0] + wsum[1] + wsum[2] + wsum[3]) / (float)NPAIR;
}

extern "C" void kernel_launch(void* const* d_in, const int* in_sizes, int n_in,
                              void* d_out, int out_size, void* d_ws, size_t ws_size,
                              hipStream_t stream) {
    const int*    labels = (const int*)d_in[1];     // cluster_labels (int32)
    const float2* coords = (const float2*)d_in[2];  // manifold_coords [8192,2] f32
    float* out    = (float*)d_out;
    float* hinges = (float*)d_ws;

    dim3 grid(K_CL, K_CL);
    pair_kernel<<<grid, 256, 0, stream>>>(labels, coords, hinges);
    reduce_hinge_kernel<<<1, 256, 0, stream>>>(hinges, out);
}

// Round 11
// 43.766 us; speedup vs baseline: 5.8891x; 1.0925x over previous
//
#include <hip/hip_runtime.h>

#define B_N 8192
#define K_CL 64
#define CAP 256
#define NPAIR 2016
#define INF_F 3.0e38f

// Pipeline (launch boundaries measured ~sub-us in graph replay; the R6
// bottleneck was the ballot-chain gather, not launches):
//  1) scatter_kernel (128 blocks x 64 thr, 1 point/thread): pos =
//     atomicAdd(cnts[label]) (native int RMW, 64 addresses), store
//     lists[label*CAP+pos]. List order is timing-dependent but min() is
//     exactly associative/commutative -> output bit-deterministic.
//  2) pair_min_kernel (64x64, ci<cj): byte-identical R6 proven kernel.
//  3) reduce_hinge_kernel (1 block): mean -> out.
// ws: lists float2[64*256] | cnts int[64] | hinges float[64*64]

__global__ __launch_bounds__(64) void scatter_kernel(
    const int* __restrict__ labels, const float2* __restrict__ coords,
    float2* __restrict__ lists, int* __restrict__ cnts) {
    int i = blockIdx.x * 64 + threadIdx.x;
    int l = labels[i];
    float2 c = coords[i];
    int pos = atomicAdd(&cnts[l], 1);
    if (pos < CAP) lists[l * CAP + pos] = c;
}

__global__ __launch_bounds__(256) void pair_min_kernel(
    const float2* __restrict__ lists, const int* __restrict__ cnts,
    float* __restrict__ hinges) {
    int ci = blockIdx.x, cj = blockIdx.y;
    if (ci >= cj) return;                 // uniform per block
    int nI = min(cnts[ci], CAP), nJ = min(cnts[cj], CAP);
    int tid = threadIdx.x;
    __shared__ float2 jpt[CAP];
    if (tid < nJ) jpt[tid] = lists[cj * CAP + tid];
    bool valid = tid < nI;
    float2 pi = make_float2(0.0f, 0.0f);
    if (valid) pi = lists[ci * CAP + tid];
    __syncthreads();

    // 4 accumulators to break the fminf dependency chain
    float m0 = INF_F, m1 = INF_F, m2 = INF_F, m3 = INF_F;
    if (valid) {
        int j = 0;
        for (; j + 3 < nJ; j += 4) {
            float2 a = jpt[j], b = jpt[j + 1], c = jpt[j + 2], d = jpt[j + 3];
            float dx0 = pi.x - a.x, dy0 = pi.y - a.y;
            float dx1 = pi.x - b.x, dy1 = pi.y - b.y;
            float dx2 = pi.x - c.x, dy2 = pi.y - c.y;
            float dx3 = pi.x - d.x, dy3 = pi.y - d.y;
            m0 = fminf(m0, dx0 * dx0 + dy0 * dy0);
            m1 = fminf(m1, dx1 * dx1 + dy1 * dy1);
            m2 = fminf(m2, dx2 * dx2 + dy2 * dy2);
            m3 = fminf(m3, dx3 * dx3 + dy3 * dy3);
        }
        for (; j < nJ; ++j) {
            float dx = pi.x - jpt[j].x, dy = pi.y - jpt[j].y;
            m0 = fminf(m0, dx * dx + dy * dy);
        }
    }
    float myMin = fminf(fminf(m0, m1), fminf(m2, m3));

    // block-reduce min: wave64 shuffle then LDS across 4 waves
    for (int off = 32; off > 0; off >>= 1)
        myMin = fminf(myMin, __shfl_down(myMin, off, 64));
    __shared__ float wmin[4];
    int wave = tid >> 6, lane = tid & 63;
    if (lane == 0) wmin[wave] = myMin;
    __syncthreads();
    if (tid == 0) {
        float m = fminf(fminf(wmin[0], wmin[1]), fminf(wmin[2], wmin[3]));
        float h = 1.0f - sqrtf(m);
        hinges[ci * K_CL + cj] = h > 0.0f ? h : 0.0f;
    }
}

__global__ void reduce_hinge_kernel(const float* __restrict__ hinges,
                                    float* __restrict__ out) {
    int tid = threadIdx.x;
    float s = 0.0f;
    for (int p = tid; p < K_CL * K_CL; p += 256) {
        int ci = p >> 6, cj = p & 63;
        if (ci < cj) s += hinges[p];
    }
    for (int off = 32; off > 0; off >>= 1)
        s += __shfl_down(s, off, 64);
    __shared__ float wsum[4];
    int wave = tid >> 6, lane = tid & 63;
    if (lane == 0) wsum[wave] = s;
    __syncthreads();
    if (tid == 0)
        out[0] = (wsum[0] + wsum[1] + wsum[2] + wsum[3]) / (float)NPAIR;
}

extern "C" void kernel_launch(void* const* d_in, const int* in_sizes, int n_in,
                              void* d_out, int out_size, void* d_ws, size_t ws_size,
                              hipStream_t stream) {
    const int*    labels = (const int*)d_in[1];     // cluster_labels (int32)
    const float2* coords = (const float2*)d_in[2];  // manifold_coords [8192,2] f32
    float* out = (float*)d_out;

    float2* lists  = (float2*)d_ws;                               // 128 KB
    int*    cnts   = (int*)((char*)d_ws + 2 * K_CL * CAP * sizeof(float));
    float*  hinges = (float*)((char*)cnts + 256);

    hipMemsetAsync(cnts, 0, K_CL * sizeof(int), stream);
    scatter_kernel<<<B_N / 64, 64, 0, stream>>>(labels, coords, lists, cnts);
    dim3 grid(K_CL, K_CL);
    pair_min_kernel<<<grid, 256, 0, stream>>>(lists, cnts, hinges);
    reduce_hinge_kernel<<<1, 256, 0, stream>>>(hinges, out);
}

// Round 12
// 30.188 us; speedup vs baseline: 8.5379x; 1.4498x over previous
//
#include <hip/hip_runtime.h>

#define B_N 8192
#define K_CL 64
#define CAP 256
#define NPAIR 2016
#define INF_F 3.0e38f

// Pipeline — no memset (R9/R11: our tiny hipMemsetAsync correlated with
// +14-40us regressions), no global atomics, no cross-block sync:
//  1) gather_kernel (64 blocks, 1/cluster): two-pass register compaction.
//     Pass A: 8x int4 label loads/thread (kept in VGPRs), count matches.
//     Block exclusive scan (shfl_up + 4-wave LDS combine) -> positions.
//     Pass B: re-walk registers, write matches to lists[c] in index order
//     (deterministic), cnts[c] written once by one thread. No pre-zeroing.
//  2) pair_min_kernel (64x64, ci<cj): proven R6/R11 kernel, unchanged.
//  3) reduce_hinge_kernel (1 block): mean -> out.
// ws: lists float2[64*256] | cnts int[64] | hinges float[64*64]

__global__ __launch_bounds__(256) void gather_kernel(
    const int* __restrict__ labels, const float2* __restrict__ coords,
    float2* __restrict__ lists, int* __restrict__ cnts) {
    int c = blockIdx.x;
    int tid = threadIdx.x, lane = tid & 63, wave = tid >> 6;
    __shared__ int wsum[4];

    // Pass A: load 32 labels into registers (coalesced int4), count matches
    int4 lb[8];
#pragma unroll
    for (int k = 0; k < 8; ++k)
        lb[k] = reinterpret_cast<const int4*>(labels)[tid + k * 256];
    int mcnt = 0;
#pragma unroll
    for (int k = 0; k < 8; ++k) {
        mcnt += (lb[k].x == c) + (lb[k].y == c);
        mcnt += (lb[k].z == c) + (lb[k].w == c);
    }

    // block exclusive scan over the 256 per-thread counts
    int incl = mcnt;
#pragma unroll
    for (int d = 1; d < 64; d <<= 1) {
        int u = __shfl_up(incl, d, 64);
        if (lane >= d) incl += u;
    }
    if (lane == 63) wsum[wave] = incl;          // wave totals
    __syncthreads();
    int wbase = 0;
#pragma unroll
    for (int w = 0; w < 4; ++w) wbase += (w < wave) ? wsum[w] : 0;
    int base = wbase + incl - mcnt;             // exclusive prefix for tid
    if (tid == 255) cnts[c] = min(base + mcnt, CAP);

    // Pass B: re-walk registers, scatter matches to lists[c] in index order
    int pos = base;
#pragma unroll
    for (int k = 0; k < 8; ++k) {
        int v4 = tid + k * 256;
        int lab[4] = {lb[k].x, lb[k].y, lb[k].z, lb[k].w};
#pragma unroll
        for (int cc = 0; cc < 4; ++cc) {
            if (lab[cc] == c) {
                if (pos < CAP) lists[c * CAP + pos] = coords[v4 * 4 + cc];
                pos++;
            }
        }
    }
}

__global__ __launch_bounds__(256) void pair_min_kernel(
    const float2* __restrict__ lists, const int* __restrict__ cnts,
    float* __restrict__ hinges) {
    int ci = blockIdx.x, cj = blockIdx.y;
    if (ci >= cj) return;                 // uniform per block
    int nI = min(cnts[ci], CAP), nJ = min(cnts[cj], CAP);
    int tid = threadIdx.x;
    __shared__ float2 jpt[CAP];
    if (tid < nJ) jpt[tid] = lists[cj * CAP + tid];
    bool valid = tid < nI;
    float2 pi = make_float2(0.0f, 0.0f);
    if (valid) pi = lists[ci * CAP + tid];
    __syncthreads();

    // 4 accumulators to break the fminf dependency chain
    float m0 = INF_F, m1 = INF_F, m2 = INF_F, m3 = INF_F;
    if (valid) {
        int j = 0;
        for (; j + 3 < nJ; j += 4) {
            float2 a = jpt[j], b = jpt[j + 1], c = jpt[j + 2], d = jpt[j + 3];
            float dx0 = pi.x - a.x, dy0 = pi.y - a.y;
            float dx1 = pi.x - b.x, dy1 = pi.y - b.y;
            float dx2 = pi.x - c.x, dy2 = pi.y - c.y;
            float dx3 = pi.x - d.x, dy3 = pi.y - d.y;
            m0 = fminf(m0, dx0 * dx0 + dy0 * dy0);
            m1 = fminf(m1, dx1 * dx1 + dy1 * dy1);
            m2 = fminf(m2, dx2 * dx2 + dy2 * dy2);
            m3 = fminf(m3, dx3 * dx3 + dy3 * dy3);
        }
        for (; j < nJ; ++j) {
            float dx = pi.x - jpt[j].x, dy = pi.y - jpt[j].y;
            m0 = fminf(m0, dx * dx + dy * dy);
        }
    }
    float myMin = fminf(fminf(m0, m1), fminf(m2, m3));

    // block-reduce min: wave64 shuffle then LDS across 4 waves
    for (int off = 32; off > 0; off >>= 1)
        myMin = fminf(myMin, __shfl_down(myMin, off, 64));
    __shared__ float wmin[4];
    int wave = tid >> 6, lane = tid & 63;
    if (lane == 0) wmin[wave] = myMin;
    __syncthreads();
    if (tid == 0) {
        float m = fminf(fminf(wmin[0], wmin[1]), fminf(wmin[2], wmin[3]));
        float h = 1.0f - sqrtf(m);
        hinges[ci * K_CL + cj] = h > 0.0f ? h : 0.0f;
    }
}

__global__ void reduce_hinge_kernel(const float* __restrict__ hinges,
                                    float* __restrict__ out) {
    int tid = threadIdx.x;
    float s = 0.0f;
    for (int p = tid; p < K_CL * K_CL; p += 256) {
        int ci = p >> 6, cj = p & 63;
        if (ci < cj) s += hinges[p];
    }
    for (int off = 32; off > 0; off >>= 1)
        s += __shfl_down(s, off, 64);
    __shared__ float wsum[4];
    int wave = tid >> 6, lane = tid & 63;
    if (lane == 0) wsum[wave] = s;
    __syncthreads();
    if (tid == 0)
        out[0] = (wsum[0] + wsum[1] + wsum[2] + wsum[3]) / (float)NPAIR;
}

extern "C" void kernel_launch(void* const* d_in, const int* in_sizes, int n_in,
                              void* d_out, int out_size, void* d_ws, size_t ws_size,
                              hipStream_t stream) {
    const int*    labels = (const int*)d_in[1];     // cluster_labels (int32)
    const float2* coords = (const float2*)d_in[2];  // manifold_coords [8192,2] f32
    float* out = (float*)d_out;

    float2* lists  = (float2*)d_ws;                               // 128 KB
    int*    cnts   = (int*)((char*)d_ws + 2 * K_CL * CAP * sizeof(float));
    float*  hinges = (float*)((char*)cnts + 256);

    gather_kernel<<<K_CL, 256, 0, stream>>>(labels, coords, lists, cnts);
    dim3 grid(K_CL, K_CL);
    pair_min_kernel<<<grid, 256, 0, stream>>>(lists, cnts, hinges);
    reduce_hinge_kernel<<<1, 256, 0, stream>>>(hinges, out);
}

// Round 13
// 29.489 us; speedup vs baseline: 8.7402x; 1.0237x over previous
//
#include <hip/hip_runtime.h>

#define B_N 8192
#define K_CL 64
#define CAP 256
#define NPAIR 2016
#define INF_F 3.0e38f

// Theory R13: R6(ballot)/R12(scan) gathers both ~20us because their write
// loops contain 32 rounds of exec-masked conditional coords loads that
// serialize (~500ns each, no TLP at 64 blocks). Fix: unconditional upfront
// register preload of labels+coords (24 independent coalesced loads in
// flight), write loop is registers+stores only. No atomics, no memset.
// ws: lists float2[64*256] | cnts int[64] | hinges float[64*64]

__global__ __launch_bounds__(256) void gather_kernel(
    const int* __restrict__ labels, const float* __restrict__ coords,
    float2* __restrict__ lists, int* __restrict__ cnts) {
    int c = blockIdx.x;
    int tid = threadIdx.x, lane = tid & 63, wave = tid >> 6;
    __shared__ int wsum[4];

    // upfront unconditional loads into registers (full memory-level parallelism)
    int4 lb[8];
    float4 cr[16];
    const int4*   l4 = reinterpret_cast<const int4*>(labels);
    const float4* c4 = reinterpret_cast<const float4*>(coords);
#pragma unroll
    for (int k = 0; k < 8; ++k) {
        int v4 = tid + k * 256;
        lb[k]       = l4[v4];
        cr[2*k]     = c4[2*v4];        // points 4*v4+0, 4*v4+1 (x,y,x,y)
        cr[2*k + 1] = c4[2*v4 + 1];    // points 4*v4+2, 4*v4+3
    }
    int mcnt = 0;
#pragma unroll
    for (int k = 0; k < 8; ++k)
        mcnt += (lb[k].x==c) + (lb[k].y==c) + (lb[k].z==c) + (lb[k].w==c);

    // block exclusive scan (wave shfl_up + 4-wave LDS combine)
    int incl = mcnt;
#pragma unroll
    for (int d = 1; d < 64; d <<= 1) {
        int u = __shfl_up(incl, d, 64);
        if (lane >= d) incl += u;
    }
    if (lane == 63) wsum[wave] = incl;
    __syncthreads();
    int wbase = 0;
#pragma unroll
    for (int w = 0; w < 4; ++w) wbase += (w < wave) ? wsum[w] : 0;
    int base = wbase + incl - mcnt;
    if (tid == 255) cnts[c] = min(base + mcnt, CAP);

    // write loop: registers + stores only, no loads in the conditional chain
    int pos = base;
#pragma unroll
    for (int k = 0; k < 8; ++k) {
        float2 p0 = make_float2(cr[2*k].x,     cr[2*k].y);
        float2 p1 = make_float2(cr[2*k].z,     cr[2*k].w);
        float2 p2 = make_float2(cr[2*k + 1].x, cr[2*k + 1].y);
        float2 p3 = make_float2(cr[2*k + 1].z, cr[2*k + 1].w);
        if (lb[k].x == c) { if (pos < CAP) lists[c*CAP + pos] = p0; pos++; }
        if (lb[k].y == c) { if (pos < CAP) lists[c*CAP + pos] = p1; pos++; }
        if (lb[k].z == c) { if (pos < CAP) lists[c*CAP + pos] = p2; pos++; }
        if (lb[k].w == c) { if (pos < CAP) lists[c*CAP + pos] = p3; pos++; }
    }
}

__global__ __launch_bounds__(256) void pair_min_kernel(
    const float2* __restrict__ lists, const int* __restrict__ cnts,
    float* __restrict__ hinges) {
    int ci = blockIdx.x, cj = blockIdx.y;
    if (ci >= cj) return;                 // uniform per block
    int nI = min(cnts[ci], CAP), nJ = min(cnts[cj], CAP);
    int tid = threadIdx.x;
    __shared__ float2 ipt[CAP], jpt[CAP];
    if (tid < nJ) jpt[tid] = lists[cj * CAP + tid];
    if (tid < nI) ipt[tid] = lists[ci * CAP + tid];
    __syncthreads();

    // 2 threads per i-point (all 256 threads active), 4-acc unrolled j-half
    int half = (nJ + 1) >> 1;
    int j0 = (tid & 1) ? half : 0;
    int j1 = (tid & 1) ? nJ : half;
    float m0 = INF_F, m1 = INF_F, m2 = INF_F, m3 = INF_F;
    for (int i = tid >> 1; i < nI; i += 128) {
        float2 pi = ipt[i];
        int j = j0;
        for (; j + 3 < j1; j += 4) {
            float2 a = jpt[j], b = jpt[j+1], c = jpt[j+2], d = jpt[j+3];
            float dx0 = pi.x - a.x, dy0 = pi.y - a.y;
            float dx1 = pi.x - b.x, dy1 = pi.y - b.y;
            float dx2 = pi.x - c.x, dy2 = pi.y - c.y;
            float dx3 = pi.x - d.x, dy3 = pi.y - d.y;
            m0 = fminf(m0, dx0*dx0 + dy0*dy0);
            m1 = fminf(m1, dx1*dx1 + dy1*dy1);
            m2 = fminf(m2, dx2*dx2 + dy2*dy2);
            m3 = fminf(m3, dx3*dx3 + dy3*dy3);
        }
        for (; j < j1; ++j) {
            float dx = pi.x - jpt[j].x, dy = pi.y - jpt[j].y;
            m0 = fminf(m0, dx*dx + dy*dy);
        }
    }
    float myMin = fminf(fminf(m0, m1), fminf(m2, m3));

    for (int off = 32; off > 0; off >>= 1)
        myMin = fminf(myMin, __shfl_down(myMin, off, 64));
    __shared__ float wmin[4];
    int wave = tid >> 6, lane = tid & 63;
    if (lane == 0) wmin[wave] = myMin;
    __syncthreads();
    if (tid == 0) {
        float m = fminf(fminf(wmin[0], wmin[1]), fminf(wmin[2], wmin[3]));
        float h = 1.0f - sqrtf(m);
        hinges[ci * K_CL + cj] = h > 0.0f ? h : 0.0f;
    }
}

__global__ void reduce_hinge_kernel(const float* __restrict__ hinges,
                                    float* __restrict__ out) {
    int tid = threadIdx.x;
    float s = 0.0f;
    for (int p = tid; p < K_CL * K_CL; p += 256) {
        int ci = p >> 6, cj = p & 63;
        if (ci < cj) s += hinges[p];
    }
    for (int off = 32; off > 0; off >>= 1)
        s += __shfl_down(s, off, 64);
    __shared__ float wsum[4];
    int wave = tid >> 6, lane = tid & 63;
    if (lane == 0) wsum[wave] = s;
    __syncthreads();
    if (tid == 0)
        out[0] = (wsum[0] + wsum[1] + wsum[2] + wsum[3]) / (float)NPAIR;
}

extern "C" void kernel_launch(void* const* d_in, const int* in_sizes, int n_in,
                              void* d_out, int out_size, void* d_ws, size_t ws_size,
                              hipStream_t stream) {
    const int*   labels = (const int*)d_in[1];     // cluster_labels (int32)
    const float* coords = (const float*)d_in[2];   // manifold_coords [8192,2] f32
    float* out = (float*)d_out;

    float2* lists  = (float2*)d_ws;                               // 128 KB
    int*    cnts   = (int*)((char*)d_ws + 2 * K_CL * CAP * sizeof(float));
    float*  hinges = (float*)((char*)cnts + 256);

    gather_kernel<<<K_CL, 256, 0, stream>>>(labels, coords, lists, cnts);
    dim3 grid(K_CL, K_CL);
    pair_min_kernel<<<grid, 256, 0, stream>>>(lists, cnts, hinges);
    reduce_hinge_kernel<<<1, 256, 0, stream>>>(hinges, out);
}